// Round 7
// baseline (636.499 us; speedup 1.0000x reference)
//
#include <hip/hip_runtime.h>
#include <hip/hip_bf16.h>
#include <math.h>

#define D_MODEL 1024
#define D_FF    4096
#define NE      8
#define NTOK    4096   // 2*2048
#define MAXTOK  4096

#define MAXROWS 10240  // 8192 + 8*255 padding, 256-aligned
#define MAXMT   40     // MAXROWS/256
#define MSUP    10     // MAXMT/4

typedef __attribute__((ext_vector_type(8))) short short8;
typedef __attribute__((ext_vector_type(4))) float f32x4;

// ---- workspace layout ----
#define WS_CNT     0
#define WS_OFFA    128
#define WS_TOKIDS  1024
#define WS_TOKW    (WS_TOKIDS + NE*MAXTOK*4)      // 132096
#define WS_ROWTOK  (WS_TOKW + NE*MAXTOK*4)        // 263168
#define WS_ROWW    (WS_ROWTOK + MAXROWS*4)        // 304128
#define WS_TOKEXP  (WS_ROWW + MAXROWS*4)          // 345088

#define WS_H       524288
#define WS_W1T     (WS_H   + (size_t)MAXROWS*D_FF*2)        // +83.9MB
#define WS_XG      (WS_W1T + (size_t)NE*D_MODEL*D_FF*2)     // +67.1MB
#define WS_W2T     (WS_XG  + (size_t)MAXROWS*D_MODEL*2)     // +21.0MB
#define WS_NEED_A  (WS_W2T + (size_t)NE*D_MODEL*D_FF*2)     // 239,599,616

__device__ __forceinline__ ushort f2b(float v) {
    __hip_bfloat16 b = __float2bfloat16(v);
    return *reinterpret_cast<ushort*>(&b);
}

// fast exact-erf GELU (Abramowitz-Stegun 7.1.26, |erf err| <= 1.5e-7)
__device__ __forceinline__ float gelu_f(float v) {
    float z = fabsf(v) * 0.70710678118654752f;
    float t = 1.0f / (1.0f + 0.3275911f * z);
    float p = t * (0.254829592f + t * (-0.284496736f + t * (1.421413741f + t * (-1.453152027f + t * 1.061405429f))));
    float er = 1.0f - p * __expf(-z * z);
    float s = (v >= 0.0f) ? er : -er;
    return 0.5f * v * (1.0f + s);
}

// bijective XCD-chunked swizzle (m204): consecutive LOGICAL ids -> same XCD
__device__ __forceinline__ int xcd_swz(int orig, int nwg) {
    int q = nwg >> 3, r = nwg & 7;
    int xcd = orig & 7, pos = orig >> 3;
    return (xcd < r ? xcd * (q + 1) : r * (q + 1) + (xcd - r) * q) + pos;
}

// ---------------- gating ----------------
__global__ __launch_bounds__(256) void gating_kernel(
    const float* __restrict__ x, const float* __restrict__ Wg, const float* __restrict__ bg,
    int* __restrict__ cnt, int* __restrict__ tok_ids, float* __restrict__ tok_w)
{
    __shared__ float s_wg[D_MODEL * NE];
    int tid = threadIdx.x;
    for (int i = tid; i < D_MODEL * NE; i += 256) s_wg[i] = Wg[i];
    __syncthreads();

    int t = blockIdx.x * 256 + tid;
    float acc[NE];
    #pragma unroll
    for (int e = 0; e < NE; ++e) acc[e] = bg[e];
    const float* xr = x + (size_t)t * D_MODEL;
    for (int d = 0; d < D_MODEL; d += 4) {
        float4 xv = *reinterpret_cast<const float4*>(xr + d);
        #pragma unroll
        for (int e = 0; e < NE; ++e) {
            acc[e] += xv.x * s_wg[(d + 0) * NE + e];
            acc[e] += xv.y * s_wg[(d + 1) * NE + e];
            acc[e] += xv.z * s_wg[(d + 2) * NE + e];
            acc[e] += xv.w * s_wg[(d + 3) * NE + e];
        }
    }
    int i0 = 0;
    #pragma unroll
    for (int e = 1; e < NE; ++e) if (acc[e] > acc[i0]) i0 = e;
    int i1 = (i0 == 0) ? 1 : 0;
    #pragma unroll
    for (int e = 0; e < NE; ++e) if (e != i0 && acc[e] > acc[i1]) i1 = e;
    float e1 = __expf(acc[i1] - acc[i0]);
    float inv = 1.0f / (1.0f + e1);
    float w0 = inv, w1 = e1 * inv;

    int p0 = atomicAdd(&cnt[i0], 1);
    tok_ids[i0 * MAXTOK + p0] = t;  tok_w[i0 * MAXTOK + p0] = w0;
    int p1 = atomicAdd(&cnt[i1], 1);
    tok_ids[i1 * MAXTOK + p1] = t;  tok_w[i1 * MAXTOK + p1] = w1;
}

// ---------------- scan: 256-aligned per-expert row offsets ----------------
__global__ void scan256_kernel(const int* __restrict__ cnt, int* __restrict__ off) {
    if (threadIdx.x == 0) {
        int acc = 0;
        for (int e = 0; e < NE; ++e) { off[e] = acc; acc += ((cnt[e] + 255) & ~255); }
        off[NE] = acc;
    }
}

// ---------------- gather: x rows -> compact bf16 Xg (16B-slot radix-8 swizzled) ----------------
__global__ __launch_bounds__(256) void gather_kernel(
    const float* __restrict__ x, const int* __restrict__ cnt, const int* __restrict__ off,
    const int* __restrict__ tok_ids, const float* __restrict__ tok_w,
    ushort* __restrict__ Xg, int* __restrict__ rowtok, float* __restrict__ roww)
{
    int e = blockIdx.y;
    int npad = off[e + 1] - off[e];
    int r0 = blockIdx.x * 128;
    if (r0 >= npad) return;
    int n = cnt[e];
    int base = off[e];
    for (int idx = threadIdx.x; idx < 128 * 128; idx += 256) {
        int r = r0 + (idx >> 7);
        int s = idx & 127;
        int R = base + r;
        int tok = -1;
        float4 v0 = {0, 0, 0, 0}, v1 = {0, 0, 0, 0};
        if (r < n) {
            tok = tok_ids[e * MAXTOK + r];
            const float4* src = (const float4*)(x + (size_t)tok * D_MODEL + s * 8);
            v0 = src[0]; v1 = src[1];
        }
        ushort o[8];
        o[0] = f2b(v0.x); o[1] = f2b(v0.y); o[2] = f2b(v0.z); o[3] = f2b(v0.w);
        o[4] = f2b(v1.x); o[5] = f2b(v1.y); o[6] = f2b(v1.z); o[7] = f2b(v1.w);
        int c = s >> 3, sub = s & 7;
        int ds = sub ^ (R & 7);
        *(uint4*)(Xg + (size_t)R * D_MODEL + c * 64 + ds * 8) = *(const uint4*)o;
        if (s == 0) {
            rowtok[R] = tok;
            roww[R] = (tok >= 0) ? tok_w[e * MAXTOK + r] : 0.0f;
        }
    }
}

// ---------------- fused weight transpose+convert (W1 and W2 in one launch) ----------------
__global__ __launch_bounds__(256) void wconv_all(
    const float* __restrict__ W1, const float* __restrict__ W2,
    ushort* __restrict__ W1T, ushort* __restrict__ W2T)
{
    __shared__ float st[64][65];
    int z = blockIdx.y;   // 0..7 -> W1 expert z ; 8..15 -> W2 expert z-8
    const float* s; ushort* d; int K, N;
    if (z < 8) { s = W1 + (size_t)z * D_MODEL * D_FF;       d = W1T + (size_t)z * D_MODEL * D_FF; K = D_MODEL; N = D_FF; }
    else       { s = W2 + (size_t)(z - 8) * D_FF * D_MODEL; d = W2T + (size_t)(z - 8) * D_FF * D_MODEL; K = D_FF; N = D_MODEL; }
    int nblk = N >> 6;
    int bx = blockIdx.x;
    int n0 = (bx % nblk) * 64;
    int k0 = (bx / nblk) * 64;
    for (int i = threadIdx.x; i < 4096; i += 256) {
        int kr = i >> 6, nc = i & 63;
        st[kr][nc] = s[(size_t)(k0 + kr) * N + n0 + nc];
    }
    __syncthreads();
    int c = k0 >> 6;
    #pragma unroll
    for (int it = 0; it < 2; ++it) {
        int v = threadIdx.x + it * 256;
        int nl = v >> 3, sub = v & 7;
        ushort o[8];
        #pragma unroll
        for (int j = 0; j < 8; ++j) o[j] = f2b(st[sub * 8 + j][nl]);
        int ds = sub ^ ((n0 + nl) & 7);
        *(uint4*)(d + (size_t)(n0 + nl) * K + c * 64 + ds * 8) = *(const uint4*)o;
    }
}

// ================= 256x256 GEMMs, r4 2-phase dbuf + supertile L2 blocking =========

// GEMM1: H = gelu(Xg @ W1 + b1). Supertiles 4mt x 4nt (A 2MB + B 2MB ~ L2/XCD).
__global__ __launch_bounds__(512, 2) void gemm1_256(
    const ushort* __restrict__ Xg, const ushort* __restrict__ W1T,
    const float* __restrict__ b1, const int* __restrict__ off,
    ushort* __restrict__ H)
{
    __shared__ ushort smem[65536];  // 128 KB
    int wid = xcd_swz(blockIdx.x, MSUP * 4 * 16);
    int S = wid >> 4, t16 = wid & 15;
    int msup = S >> 2, nsup = S & 3;
    int mt = msup * 4 + (t16 & 3);
    int nt = nsup * 4 + (t16 >> 2);
    int row0 = mt << 8;
    if (row0 >= off[NE]) return;
    int e = 0;
    #pragma unroll
    for (int i = 1; i < NE; ++i) if (off[i] <= row0) e = i;
    int nb0 = nt << 8;
    int tid = threadIdx.x;
    int lane = tid & 63, wave = tid >> 6;
    int wr = wave >> 2, wc = wave & 3;

    const ushort* Abase = Xg + (size_t)row0 * D_MODEL;
    const ushort* Bbase = W1T + ((size_t)e * D_FF + nb0) * D_MODEL;

    f32x4 acc[8][4];
    #pragma unroll
    for (int m = 0; m < 8; ++m)
        #pragma unroll
        for (int n = 0; n < 4; ++n)
            acc[m][n] = (f32x4){0.f, 0.f, 0.f, 0.f};

    #define STAGE1(buf, kt) { \
        _Pragma("unroll") \
        for (int r = 0; r < 4; ++r) { \
            int flat = r * 512 + tid; int row_ = flat >> 3, sl = flat & 7; \
            __builtin_amdgcn_global_load_lds((const __attribute__((address_space(1))) void*)(Abase + (size_t)row_ * D_MODEL + (kt) * 64 + sl * 8), \
                (__attribute__((address_space(3))) void*)(smem + (buf) * 16384 + flat * 8), 16, 0, 0); \
            __builtin_amdgcn_global_load_lds((const __attribute__((address_space(1))) void*)(Bbase + (size_t)row_ * D_MODEL + (kt) * 64 + sl * 8), \
                (__attribute__((address_space(3))) void*)(smem + 32768 + (buf) * 16384 + flat * 8), 16, 0, 0); \
        } }

    STAGE1(0, 0);
    __syncthreads();
    for (int kt = 0; kt < 16; ++kt) {
        int cur = kt & 1;
        if (kt + 1 < 16) STAGE1(cur ^ 1, kt + 1);
        const ushort* sAc = smem + cur * 16384;
        const ushort* sBc = smem + 32768 + cur * 16384;
        #pragma unroll
        for (int ks = 0; ks < 2; ++ks) {
            int j = ks * 4 + (lane >> 4);
            short8 b[4];
            #pragma unroll
            for (int n = 0; n < 4; ++n) {
                int brow = wc * 64 + n * 16 + (lane & 15);
                b[n] = *(const short8*)(sBc + brow * 64 + (j ^ (brow & 7)) * 8);
            }
            #pragma unroll
            for (int m = 0; m < 8; ++m) {
                int arow = wr * 128 + m * 16 + (lane & 15);
                short8 a = *(const short8*)(sAc + arow * 64 + (j ^ (arow & 7)) * 8);
                #pragma unroll
                for (int n = 0; n < 4; ++n)
                    acc[m][n] = __builtin_amdgcn_mfma_f32_16x16x32_bf16(a, b[n], acc[m][n], 0, 0, 0);
            }
        }
        __syncthreads();
    }

    // epilogue: gelu -> LDS (global-swizzled layout) -> coalesced 16B stores
    const float* b1e = b1 + (size_t)e * D_FF + nb0;
    #pragma unroll
    for (int n = 0; n < 4; ++n) {
        int col = wc * 64 + n * 16 + (lane & 15);
        float bv = b1e[col];
        int gl = col >> 3, el = col & 7;
        #pragma unroll
        for (int m = 0; m < 8; ++m) {
            int rbase = wr * 128 + m * 16 + (lane >> 4) * 4;
            #pragma unroll
            for (int q = 0; q < 4; ++q) {
                int row = rbase + q;
                float v = gelu_f(acc[m][n][q] + bv);
                int g = (gl & ~7) | ((gl ^ row) & 7);
                smem[row * 256 + g * 8 + el] = f2b(v);
            }
        }
    }
    __syncthreads();
    #pragma unroll
    for (int it = 0; it < 16; ++it) {
        int flat = it * 512 + tid;
        int row = flat >> 5, g = flat & 31;
        *(uint4*)(H + (size_t)(row0 + row) * D_FF + nb0 + g * 8) = *(const uint4*)(smem + flat * 8);
    }
}

// GEMM2: out[tok] += w * (H @ W2 + b2). nks=4 K-split, fused-combine atomic epilogue.
// Supertiles: S = ks*MSUP + msup; within: 4mt x 4nt (panels 0.5MB -> 4MB/XCD).
__global__ __launch_bounds__(512, 2) void gemm2_256(
    const ushort* __restrict__ H, const ushort* __restrict__ W2T,
    const float* __restrict__ b2, const int* __restrict__ off,
    const int* __restrict__ rowtok, const float* __restrict__ roww,
    float* __restrict__ out)
{
    __shared__ ushort smem[65536];
    int wid = xcd_swz(blockIdx.x, 4 * MSUP * 16);
    int S = wid >> 4, t16 = wid & 15;
    int ks = S / MSUP, msup = S - ks * MSUP;
    int mt = msup * 4 + (t16 >> 2);
    int nt = t16 & 3;
    int row0 = mt << 8;
    if (row0 >= off[NE]) return;
    int e = 0;
    #pragma unroll
    for (int i = 1; i < NE; ++i) if (off[i] <= row0) e = i;
    int nb0 = nt << 8;
    int tid = threadIdx.x;
    int lane = tid & 63, wave = tid >> 6;
    int wr = wave >> 2, wc = wave & 3;
    int kt0 = ks * 16;   // 16 K-tiles of 64 per split (4 x 1024 = 4096)

    const ushort* Abase = H + (size_t)row0 * D_FF;
    const ushort* Bbase = W2T + ((size_t)e * D_MODEL + nb0) * D_FF;

    f32x4 acc[8][4];
    #pragma unroll
    for (int m = 0; m < 8; ++m)
        #pragma unroll
        for (int n = 0; n < 4; ++n)
            acc[m][n] = (f32x4){0.f, 0.f, 0.f, 0.f};

    #define STAGE2(buf, kt) { \
        _Pragma("unroll") \
        for (int r = 0; r < 4; ++r) { \
            int flat = r * 512 + tid; int row_ = flat >> 3, sl = flat & 7; \
            __builtin_amdgcn_global_load_lds((const __attribute__((address_space(1))) void*)(Abase + (size_t)row_ * D_FF + (kt) * 64 + sl * 8), \
                (__attribute__((address_space(3))) void*)(smem + (buf) * 16384 + flat * 8), 16, 0, 0); \
            __builtin_amdgcn_global_load_lds((const __attribute__((address_space(1))) void*)(Bbase + (size_t)row_ * D_FF + (kt) * 64 + sl * 8), \
                (__attribute__((address_space(3))) void*)(smem + 32768 + (buf) * 16384 + flat * 8), 16, 0, 0); \
        } }

    STAGE2(0, kt0);
    __syncthreads();
    for (int i = 0; i < 16; ++i) {
        int cur = i & 1;
        if (i + 1 < 16) STAGE2(cur ^ 1, kt0 + i + 1);
        const ushort* sAc = smem + cur * 16384;
        const ushort* sBc = smem + 32768 + cur * 16384;
        #pragma unroll
        for (int ksu = 0; ksu < 2; ++ksu) {
            int j = ksu * 4 + (lane >> 4);
            short8 b[4];
            #pragma unroll
            for (int n = 0; n < 4; ++n) {
                int brow = wc * 64 + n * 16 + (lane & 15);
                b[n] = *(const short8*)(sBc + brow * 64 + (j ^ (brow & 7)) * 8);
            }
            #pragma unroll
            for (int m = 0; m < 8; ++m) {
                int arow = wr * 128 + m * 16 + (lane & 15);
                short8 a = *(const short8*)(sAc + arow * 64 + (j ^ (arow & 7)) * 8);
                #pragma unroll
                for (int n = 0; n < 4; ++n)
                    acc[m][n] = __builtin_amdgcn_mfma_f32_16x16x32_bf16(a, b[n], acc[m][n], 0, 0, 0);
            }
        }
        __syncthreads();
    }

    // fused combine: out[tok][col] += w * (acc + (ks==0)*b2)
    const float* b2e = b2 + (size_t)e * D_MODEL + nb0;
    #pragma unroll
    for (int m = 0; m < 8; ++m) {
        int rbase = wr * 128 + m * 16 + (lane >> 4) * 4;
        #pragma unroll
        for (int q = 0; q < 4; ++q) {
            int R = row0 + rbase + q;
            int tok = rowtok[R];
            if (tok < 0) continue;
            float w = roww[R];
            float* orow = out + (size_t)tok * D_MODEL + nb0;
            #pragma unroll
            for (int n = 0; n < 4; ++n) {
                int col = wc * 64 + n * 16 + (lane & 15);
                float bv = (ks == 0) ? b2e[col] : 0.0f;
                atomicAdd(orow + col, w * (acc[m][n][q] + bv));
            }
        }
    }
}

// ================= legacy fp32 fallback =================
#define TM      32
#define FFC     128
#define KSTEP   64

__global__ __launch_bounds__(512) void ffn_kernel(
    const float* __restrict__ x,
    const float* __restrict__ W1, const float* __restrict__ b1,
    const float* __restrict__ W2, const float* __restrict__ b2,
    const int* __restrict__ cnt, const int* __restrict__ tok_ids, const float* __restrict__ tok_w,
    float* __restrict__ out)
{
    int e = blockIdx.y;
    int n = cnt[e];
    int t0 = blockIdx.x * TM;
    if (t0 >= n) return;
    int tid = threadIdx.x;

    __shared__ int   s_tok[TM];
    __shared__ float s_w[TM];
    __shared__ float s_x[TM][KSTEP];
    __shared__ float s_w1[KSTEP][FFC];
    __shared__ float s_h[TM][FFC];

    if (tid < TM) {
        int idx = t0 + tid;
        s_tok[tid] = (idx < n) ? tok_ids[e * MAXTOK + idx] : -1;
        s_w[tid]   = (idx < n) ? tok_w[e * MAXTOK + idx] : 0.0f;
    }
    __syncthreads();

    float acc[TM][2];
    #pragma unroll
    for (int i = 0; i < TM; ++i) { acc[i][0] = 0.0f; acc[i][1] = 0.0f; }

    const float* W1e = W1 + (size_t)e * D_MODEL * D_FF;
    const float* W2e = W2 + (size_t)e * D_FF * D_MODEL;
    const float* b1e = b1 + (size_t)e * D_FF;

    int ffl = (tid & 63) * 2;
    int g   = tid >> 6;

    int fb0 = blockIdx.z * (D_FF / 2);
    for (int fb = fb0; fb < fb0 + D_FF / 2; fb += FFC) {
        float bv0 = b1e[fb + ffl], bv1 = b1e[fb + ffl + 1];
        float hacc[4][2];
        #pragma unroll
        for (int j = 0; j < 4; ++j) { hacc[j][0] = bv0; hacc[j][1] = bv1; }

        for (int kb = 0; kb < D_MODEL; kb += KSTEP) {
            #pragma unroll
            for (int r = 0; r < 4; ++r) {
                int i = tid + 512 * r;
                int row = i >> 6, col = i & 63;
                int tok = s_tok[row];
                s_x[row][col] = (tok >= 0) ? x[(size_t)tok * D_MODEL + kb + col] : 0.0f;
            }
            #pragma unroll
            for (int r = 0; r < 16; ++r) {
                int i = tid + 512 * r;
                int row = i >> 7, col = i & 127;
                s_w1[row][col] = W1e[(size_t)(kb + row) * D_FF + fb + col];
            }
            __syncthreads();
            #pragma unroll 8
            for (int kk = 0; kk < KSTEP; ++kk) {
                float2 wv = *reinterpret_cast<const float2*>(&s_w1[kk][ffl]);
                #pragma unroll
                for (int j = 0; j < 4; ++j) {
                    float xv = s_x[g * 4 + j][kk];
                    hacc[j][0] += xv * wv.x;
                    hacc[j][1] += xv * wv.y;
                }
            }
            __syncthreads();
        }
        #pragma unroll
        for (int j = 0; j < 4; ++j) {
            #pragma unroll
            for (int p = 0; p < 2; ++p) {
                float v = hacc[j][p];
                v = 0.5f * v * (1.0f + erff(v * 0.70710678118654752f));
                s_h[g * 4 + j][ffl + p] = v;
            }
        }
        __syncthreads();
        for (int ff = 0; ff < FFC; ++ff) {
            const float* w2row = W2e + (size_t)(fb + ff) * D_MODEL;
            float wc0 = w2row[tid], wc1 = w2row[tid + 512];
            #pragma unroll
            for (int tt = 0; tt < TM; ++tt) {
                float hv = s_h[tt][ff];
                acc[tt][0] += hv * wc0;
                acc[tt][1] += hv * wc1;
            }
        }
        __syncthreads();
    }

    float bc0 = b2[(size_t)e * D_MODEL + tid];
    float bc1 = b2[(size_t)e * D_MODEL + tid + 512];
    if (blockIdx.z != 0) { bc0 = 0.0f; bc1 = 0.0f; }
    #pragma unroll
    for (int tt = 0; tt < TM; ++tt) {
        int tok = s_tok[tt];
        if (tok >= 0) {
            float w = s_w[tt];
            atomicAdd(&out[(size_t)tok * D_MODEL + tid],       w * (acc[tt][0] + bc0));
            atomicAdd(&out[(size_t)tok * D_MODEL + tid + 512], w * (acc[tt][1] + bc1));
        }
    }
}

extern "C" void kernel_launch(void* const* d_in, const int* in_sizes, int n_in,
                              void* d_out, int out_size, void* d_ws, size_t ws_size,
                              hipStream_t stream) {
    const float* x  = (const float*)d_in[0];
    const float* Wg = (const float*)d_in[1];
    const float* bg = (const float*)d_in[2];
    const float* W1 = (const float*)d_in[3];
    const float* b1 = (const float*)d_in[4];
    const float* W2 = (const float*)d_in[5];
    const float* b2 = (const float*)d_in[6];
    float* out = (float*)d_out;

    char* ws = (char*)d_ws;
    int*    cnt     = (int*)(ws + WS_CNT);
    int*    offp    = (int*)(ws + WS_OFFA);
    int*    tok_ids = (int*)(ws + WS_TOKIDS);
    float*  tok_w   = (float*)(ws + WS_TOKW);
    int*    rowtok  = (int*)(ws + WS_ROWTOK);
    float*  roww    = (float*)(ws + WS_ROWW);

    hipMemsetAsync(cnt, 0, NE * sizeof(int), stream);
    hipMemsetAsync(out, 0, (size_t)out_size * sizeof(float), stream);
    gating_kernel<<<NTOK / 256, 256, 0, stream>>>(x, Wg, bg, cnt, tok_ids, tok_w);

    if (ws_size >= WS_NEED_A) {
        ushort* Hb  = (ushort*)(ws + WS_H);
        ushort* W1T = (ushort*)(ws + WS_W1T);
        ushort* Xg  = (ushort*)(ws + WS_XG);
        ushort* W2T = (ushort*)(ws + WS_W2T);

        scan256_kernel<<<1, 64, 0, stream>>>(cnt, offp);
        wconv_all<<<dim3(1024, 16), 256, 0, stream>>>(W1, W2, W1T, W2T);
        gather_kernel<<<dim3(32, NE), 256, 0, stream>>>(x, cnt, offp, tok_ids, tok_w, Xg, rowtok, roww);
        gemm1_256<<<MSUP * 4 * 16, 512, 0, stream>>>(Xg, W1T, b1, offp, Hb);
        gemm2_256<<<4 * MSUP * 16, 512, 0, stream>>>(Hb, W2T, b2, offp, rowtok, roww, out);
    } else {
        dim3 grid(MAXTOK / TM, NE, 2);
        ffn_kernel<<<grid, 512, 0, stream>>>(x, W1, b1, W2, b2, cnt, tok_ids, tok_w, out);
    }
}

// Round 8
// 459.630 us; speedup vs baseline: 1.3848x; 1.3848x over previous
//
#include <hip/hip_runtime.h>
#include <hip/hip_bf16.h>
#include <math.h>

#define D_MODEL 1024
#define D_FF    4096
#define NE      8
#define NTOK    4096   // 2*2048
#define MAXTOK  4096

#define MAXROWS 10240  // 8192 + 8*255 padding, 256-aligned
#define MAXMT   40     // MAXROWS/256

typedef __attribute__((ext_vector_type(8))) short short8;
typedef __attribute__((ext_vector_type(4))) float f32x4;

// ---- workspace layout ----
#define WS_CNT     0
#define WS_OFFA    128
#define WS_TOKIDS  1024
#define WS_TOKW    (WS_TOKIDS + NE*MAXTOK*4)      // 132096
#define WS_ROWTOK  (WS_TOKW + NE*MAXTOK*4)        // 263168
#define WS_ROWW    (WS_ROWTOK + MAXROWS*4)        // 304128
#define WS_TOKEXP  (WS_ROWW + MAXROWS*4)          // 345088

#define WS_H       524288
#define WS_W1T     (WS_H   + (size_t)MAXROWS*D_FF*2)        // +83.9MB
#define WS_XG      (WS_W1T + (size_t)NE*D_MODEL*D_FF*2)     // +67.1MB
#define WS_W2T     (WS_XG  + (size_t)MAXROWS*D_MODEL*2)     // +21.0MB
#define WS_NEED_A  (WS_W2T + (size_t)NE*D_MODEL*D_FF*2)     // 239,599,616

__device__ __forceinline__ ushort f2b(float v) {
    __hip_bfloat16 b = __float2bfloat16(v);
    return *reinterpret_cast<ushort*>(&b);
}

// fast exact-erf GELU (Abramowitz-Stegun 7.1.26, |erf err| <= 1.5e-7)
__device__ __forceinline__ float gelu_f(float v) {
    float z = fabsf(v) * 0.70710678118654752f;
    float t = 1.0f / (1.0f + 0.3275911f * z);
    float p = t * (0.254829592f + t * (-0.284496736f + t * (1.421413741f + t * (-1.453152027f + t * 1.061405429f))));
    float er = 1.0f - p * __expf(-z * z);
    float s = (v >= 0.0f) ? er : -er;
    return 0.5f * v * (1.0f + s);
}

// bijective XCD-chunked swizzle (m204): consecutive LOGICAL ids -> same XCD
__device__ __forceinline__ int xcd_swz(int orig, int nwg) {
    int q = nwg >> 3, r = nwg & 7;
    int xcd = orig & 7, pos = orig >> 3;
    return (xcd < r ? xcd * (q + 1) : r * (q + 1) + (xcd - r) * q) + pos;
}

// ---------------- gating ----------------
__global__ __launch_bounds__(256) void gating_kernel(
    const float* __restrict__ x, const float* __restrict__ Wg, const float* __restrict__ bg,
    int* __restrict__ cnt, int* __restrict__ tok_ids, float* __restrict__ tok_w,
    int* __restrict__ tokexp)
{
    __shared__ float s_wg[D_MODEL * NE];
    int tid = threadIdx.x;
    for (int i = tid; i < D_MODEL * NE; i += 256) s_wg[i] = Wg[i];
    __syncthreads();

    int t = blockIdx.x * 256 + tid;
    float acc[NE];
    #pragma unroll
    for (int e = 0; e < NE; ++e) acc[e] = bg[e];
    const float* xr = x + (size_t)t * D_MODEL;
    for (int d = 0; d < D_MODEL; d += 4) {
        float4 xv = *reinterpret_cast<const float4*>(xr + d);
        #pragma unroll
        for (int e = 0; e < NE; ++e) {
            acc[e] += xv.x * s_wg[(d + 0) * NE + e];
            acc[e] += xv.y * s_wg[(d + 1) * NE + e];
            acc[e] += xv.z * s_wg[(d + 2) * NE + e];
            acc[e] += xv.w * s_wg[(d + 3) * NE + e];
        }
    }
    int i0 = 0;
    #pragma unroll
    for (int e = 1; e < NE; ++e) if (acc[e] > acc[i0]) i0 = e;
    int i1 = (i0 == 0) ? 1 : 0;
    #pragma unroll
    for (int e = 0; e < NE; ++e) if (e != i0 && acc[e] > acc[i1]) i1 = e;
    float e1 = __expf(acc[i1] - acc[i0]);
    float inv = 1.0f / (1.0f + e1);
    float w0 = inv, w1 = e1 * inv;

    int p0 = atomicAdd(&cnt[i0], 1);
    tok_ids[i0 * MAXTOK + p0] = t;  tok_w[i0 * MAXTOK + p0] = w0;
    tokexp[t * 2 + 0] = i0 * MAXTOK + p0;
    int p1 = atomicAdd(&cnt[i1], 1);
    tok_ids[i1 * MAXTOK + p1] = t;  tok_w[i1 * MAXTOK + p1] = w1;
    tokexp[t * 2 + 1] = i1 * MAXTOK + p1;
}

// ---------------- scan: 256-aligned per-expert row offsets ----------------
__global__ void scan256_kernel(const int* __restrict__ cnt, int* __restrict__ off) {
    if (threadIdx.x == 0) {
        int acc = 0;
        for (int e = 0; e < NE; ++e) { off[e] = acc; acc += ((cnt[e] + 255) & ~255); }
        off[NE] = acc;
    }
}

// ---------------- gather: x rows -> compact bf16 Xg (16B-slot radix-8 swizzled) ----------------
__global__ __launch_bounds__(256) void gather_kernel(
    const float* __restrict__ x, const int* __restrict__ cnt, const int* __restrict__ off,
    const int* __restrict__ tok_ids, const float* __restrict__ tok_w,
    ushort* __restrict__ Xg, int* __restrict__ rowtok, float* __restrict__ roww)
{
    int e = blockIdx.y;
    int npad = off[e + 1] - off[e];
    int r0 = blockIdx.x * 128;
    if (r0 >= npad) return;
    int n = cnt[e];
    int base = off[e];
    for (int idx = threadIdx.x; idx < 128 * 128; idx += 256) {
        int r = r0 + (idx >> 7);
        int s = idx & 127;
        int R = base + r;
        int tok = -1;
        float4 v0 = {0, 0, 0, 0}, v1 = {0, 0, 0, 0};
        if (r < n) {
            tok = tok_ids[e * MAXTOK + r];
            const float4* src = (const float4*)(x + (size_t)tok * D_MODEL + s * 8);
            v0 = src[0]; v1 = src[1];
        }
        ushort o[8];
        o[0] = f2b(v0.x); o[1] = f2b(v0.y); o[2] = f2b(v0.z); o[3] = f2b(v0.w);
        o[4] = f2b(v1.x); o[5] = f2b(v1.y); o[6] = f2b(v1.z); o[7] = f2b(v1.w);
        int c = s >> 3, sub = s & 7;
        int ds = sub ^ (R & 7);
        *(uint4*)(Xg + (size_t)R * D_MODEL + c * 64 + ds * 8) = *(const uint4*)o;
        if (s == 0) {
            rowtok[R] = tok;
            roww[R] = (tok >= 0) ? tok_w[e * MAXTOK + r] : 0.0f;
        }
    }
}

// ---------------- fused weight transpose+convert (W1 and W2 in one launch) ----------------
__global__ __launch_bounds__(256) void wconv_all(
    const float* __restrict__ W1, const float* __restrict__ W2,
    ushort* __restrict__ W1T, ushort* __restrict__ W2T)
{
    __shared__ float st[64][65];
    int z = blockIdx.y;   // 0..7 -> W1 expert z ; 8..15 -> W2 expert z-8
    const float* s; ushort* d; int K, N;
    if (z < 8) { s = W1 + (size_t)z * D_MODEL * D_FF;       d = W1T + (size_t)z * D_MODEL * D_FF; K = D_MODEL; N = D_FF; }
    else       { s = W2 + (size_t)(z - 8) * D_FF * D_MODEL; d = W2T + (size_t)(z - 8) * D_FF * D_MODEL; K = D_FF; N = D_MODEL; }
    int nblk = N >> 6;
    int bx = blockIdx.x;
    int n0 = (bx % nblk) * 64;
    int k0 = (bx / nblk) * 64;
    for (int i = threadIdx.x; i < 4096; i += 256) {
        int kr = i >> 6, nc = i & 63;
        st[kr][nc] = s[(size_t)(k0 + kr) * N + n0 + nc];
    }
    __syncthreads();
    int c = k0 >> 6;
    #pragma unroll
    for (int it = 0; it < 2; ++it) {
        int v = threadIdx.x + it * 256;
        int nl = v >> 3, sub = v & 7;
        ushort o[8];
        #pragma unroll
        for (int j = 0; j < 8; ++j) o[j] = f2b(st[sub * 8 + j][nl]);
        int ds = sub ^ ((n0 + nl) & 7);
        *(uint4*)(d + (size_t)(n0 + nl) * K + c * 64 + ds * 8) = *(const uint4*)o;
    }
}

// ================= 256x256 GEMMs (r4 2-phase dbuf structure) =================

// GEMM1: H = gelu(Xg @ W1 + b1). r4-exact (control): mt-major decode.
__global__ __launch_bounds__(512, 2) void gemm1_256(
    const ushort* __restrict__ Xg, const ushort* __restrict__ W1T,
    const float* __restrict__ b1, const int* __restrict__ off,
    ushort* __restrict__ H)
{
    __shared__ ushort smem[65536];  // 128 KB
    int wid = xcd_swz(blockIdx.x, MAXMT * 16);
    int mt = wid >> 4, nt = wid & 15;
    int row0 = mt << 8;
    if (row0 >= off[NE]) return;
    int e = 0;
    #pragma unroll
    for (int i = 1; i < NE; ++i) if (off[i] <= row0) e = i;
    int nb0 = nt << 8;
    int tid = threadIdx.x;
    int lane = tid & 63, wave = tid >> 6;
    int wr = wave >> 2, wc = wave & 3;

    const ushort* Abase = Xg + (size_t)row0 * D_MODEL;
    const ushort* Bbase = W1T + ((size_t)e * D_FF + nb0) * D_MODEL;

    f32x4 acc[8][4];
    #pragma unroll
    for (int m = 0; m < 8; ++m)
        #pragma unroll
        for (int n = 0; n < 4; ++n)
            acc[m][n] = (f32x4){0.f, 0.f, 0.f, 0.f};

    #define STAGE1(buf, kt) { \
        _Pragma("unroll") \
        for (int r = 0; r < 4; ++r) { \
            int flat = r * 512 + tid; int row_ = flat >> 3, sl = flat & 7; \
            __builtin_amdgcn_global_load_lds((const __attribute__((address_space(1))) void*)(Abase + (size_t)row_ * D_MODEL + (kt) * 64 + sl * 8), \
                (__attribute__((address_space(3))) void*)(smem + (buf) * 16384 + flat * 8), 16, 0, 0); \
            __builtin_amdgcn_global_load_lds((const __attribute__((address_space(1))) void*)(Bbase + (size_t)row_ * D_MODEL + (kt) * 64 + sl * 8), \
                (__attribute__((address_space(3))) void*)(smem + 32768 + (buf) * 16384 + flat * 8), 16, 0, 0); \
        } }

    STAGE1(0, 0);
    __syncthreads();
    for (int kt = 0; kt < 16; ++kt) {
        int cur = kt & 1;
        if (kt + 1 < 16) STAGE1(cur ^ 1, kt + 1);
        const ushort* sAc = smem + cur * 16384;
        const ushort* sBc = smem + 32768 + cur * 16384;
        #pragma unroll
        for (int ks = 0; ks < 2; ++ks) {
            int j = ks * 4 + (lane >> 4);
            short8 b[4];
            #pragma unroll
            for (int n = 0; n < 4; ++n) {
                int brow = wc * 64 + n * 16 + (lane & 15);
                b[n] = *(const short8*)(sBc + brow * 64 + (j ^ (brow & 7)) * 8);
            }
            #pragma unroll
            for (int m = 0; m < 8; ++m) {
                int arow = wr * 128 + m * 16 + (lane & 15);
                short8 a = *(const short8*)(sAc + arow * 64 + (j ^ (arow & 7)) * 8);
                #pragma unroll
                for (int n = 0; n < 4; ++n)
                    acc[m][n] = __builtin_amdgcn_mfma_f32_16x16x32_bf16(a, b[n], acc[m][n], 0, 0, 0);
            }
        }
        __syncthreads();
    }

    // epilogue: gelu -> LDS (global-swizzled layout) -> coalesced 16B stores
    const float* b1e = b1 + (size_t)e * D_FF + nb0;
    #pragma unroll
    for (int n = 0; n < 4; ++n) {
        int col = wc * 64 + n * 16 + (lane & 15);
        float bv = b1e[col];
        int gl = col >> 3, el = col & 7;
        #pragma unroll
        for (int m = 0; m < 8; ++m) {
            int rbase = wr * 128 + m * 16 + (lane >> 4) * 4;
            #pragma unroll
            for (int q = 0; q < 4; ++q) {
                int row = rbase + q;
                float v = gelu_f(acc[m][n][q] + bv);
                int g = (gl & ~7) | ((gl ^ row) & 7);
                smem[row * 256 + g * 8 + el] = f2b(v);
            }
        }
    }
    __syncthreads();
    #pragma unroll
    for (int it = 0; it < 16; ++it) {
        int flat = it * 512 + tid;
        int row = flat >> 5, g = flat & 31;
        *(uint4*)(H + (size_t)(row0 + row) * D_FF + nb0 + g * 8) = *(const uint4*)(smem + flat * 8);
    }
}

// GEMM2: Y[ks] = H @ W2 (K-split 2) + (ks==0 ? b2 : 0). Plain f32 stores.
// EXPERIMENT: B-panel-major decode — each XCD owns exactly one (nt,ks) group
// (grid 320 = 8 XCDs x 40 mt blocks), so its 1MB W2T panel stays L2-resident.
__global__ __launch_bounds__(512, 2) void gemm2_256(
    const ushort* __restrict__ H, const ushort* __restrict__ W2T,
    const float* __restrict__ b2, const int* __restrict__ off,
    float* __restrict__ Y)
{
    __shared__ ushort smem[65536];
    int wid = xcd_swz(blockIdx.x, MAXMT * 8);
    int nt = wid / (2 * MAXMT);           // 0..3
    int ks = (wid / MAXMT) & 1;           // 0..1
    int mt = wid % MAXMT;                 // 0..39 (fastest within XCD chunk)
    int row0 = mt << 8;
    if (row0 >= off[NE]) return;
    int e = 0;
    #pragma unroll
    for (int i = 1; i < NE; ++i) if (off[i] <= row0) e = i;
    int nb0 = nt << 8;
    int tid = threadIdx.x;
    int lane = tid & 63, wave = tid >> 6;
    int wr = wave >> 2, wc = wave & 3;
    int kt0 = ks * 32;

    const ushort* Abase = H + (size_t)row0 * D_FF;
    const ushort* Bbase = W2T + ((size_t)e * D_MODEL + nb0) * D_FF;

    f32x4 acc[8][4];
    #pragma unroll
    for (int m = 0; m < 8; ++m)
        #pragma unroll
        for (int n = 0; n < 4; ++n)
            acc[m][n] = (f32x4){0.f, 0.f, 0.f, 0.f};

    #define STAGE2(buf, kt) { \
        _Pragma("unroll") \
        for (int r = 0; r < 4; ++r) { \
            int flat = r * 512 + tid; int row_ = flat >> 3, sl = flat & 7; \
            __builtin_amdgcn_global_load_lds((const __attribute__((address_space(1))) void*)(Abase + (size_t)row_ * D_FF + (kt) * 64 + sl * 8), \
                (__attribute__((address_space(3))) void*)(smem + (buf) * 16384 + flat * 8), 16, 0, 0); \
            __builtin_amdgcn_global_load_lds((const __attribute__((address_space(1))) void*)(Bbase + (size_t)row_ * D_FF + (kt) * 64 + sl * 8), \
                (__attribute__((address_space(3))) void*)(smem + 32768 + (buf) * 16384 + flat * 8), 16, 0, 0); \
        } }

    STAGE2(0, kt0);
    __syncthreads();
    for (int i = 0; i < 32; ++i) {
        int cur = i & 1;
        if (i + 1 < 32) STAGE2(cur ^ 1, kt0 + i + 1);
        const ushort* sAc = smem + cur * 16384;
        const ushort* sBc = smem + 32768 + cur * 16384;
        #pragma unroll
        for (int ksu = 0; ksu < 2; ++ksu) {
            int j = ksu * 4 + (lane >> 4);
            short8 b[4];
            #pragma unroll
            for (int n = 0; n < 4; ++n) {
                int brow = wc * 64 + n * 16 + (lane & 15);
                b[n] = *(const short8*)(sBc + brow * 64 + (j ^ (brow & 7)) * 8);
            }
            #pragma unroll
            for (int m = 0; m < 8; ++m) {
                int arow = wr * 128 + m * 16 + (lane & 15);
                short8 a = *(const short8*)(sAc + arow * 64 + (j ^ (arow & 7)) * 8);
                #pragma unroll
                for (int n = 0; n < 4; ++n)
                    acc[m][n] = __builtin_amdgcn_mfma_f32_16x16x32_bf16(a, b[n], acc[m][n], 0, 0, 0);
            }
        }
        __syncthreads();
    }

    float* Yb = Y + (size_t)ks * MAXROWS * D_MODEL;
    const float* b2e = b2 + (size_t)e * D_MODEL + nb0;
    #pragma unroll
    for (int n = 0; n < 4; ++n) {
        int col = wc * 64 + n * 16 + (lane & 15);
        float bv = (ks == 0) ? b2e[col] : 0.0f;
        #pragma unroll
        for (int m = 0; m < 8; ++m) {
            int rbase = wr * 128 + m * 16 + (lane >> 4) * 4;
            #pragma unroll
            for (int q = 0; q < 4; ++q)
                Yb[(size_t)(row0 + rbase + q) * D_MODEL + nb0 + col] = acc[m][n][q] + bv;
        }
    }
}

// combine: out[t] = sum_k w_k * sum_s Y_s[R_k]
__global__ __launch_bounds__(256) void combine_kernel(
    const float* __restrict__ Y, const int* __restrict__ off,
    const int* __restrict__ tokexp, const float* __restrict__ tok_w,
    float* __restrict__ out, int nks)
{
    int t = blockIdx.x;
    int pos0 = tokexp[2 * t], pos1 = tokexp[2 * t + 1];
    int e0 = pos0 >> 12, p0 = pos0 & (MAXTOK - 1);
    int e1 = pos1 >> 12, p1 = pos1 & (MAXTOK - 1);
    size_t R0 = off[e0] + p0, R1 = off[e1] + p1;
    float w0 = tok_w[pos0], w1 = tok_w[pos1];
    int c = threadIdx.x * 4;
    float y0x = 0, y0y = 0, y0z = 0, y0w = 0;
    float y1x = 0, y1y = 0, y1z = 0, y1w = 0;
    for (int s = 0; s < nks; ++s) {
        const float* Ys = Y + (size_t)s * MAXROWS * D_MODEL;
        float4 a = *(const float4*)(Ys + R0 * D_MODEL + c);
        float4 b = *(const float4*)(Ys + R1 * D_MODEL + c);
        y0x += a.x; y0y += a.y; y0z += a.z; y0w += a.w;
        y1x += b.x; y1y += b.y; y1z += b.z; y1w += b.w;
    }
    float4 o;
    o.x = w0 * y0x + w1 * y1x;
    o.y = w0 * y0y + w1 * y1y;
    o.z = w0 * y0z + w1 * y1z;
    o.w = w0 * y0w + w1 * y1w;
    *(float4*)(out + (size_t)t * D_MODEL + c) = o;
}

// ================= legacy fp32 fallback =================
#define TM      32
#define FFC     128
#define KSTEP   64

__global__ __launch_bounds__(512) void ffn_kernel(
    const float* __restrict__ x,
    const float* __restrict__ W1, const float* __restrict__ b1,
    const float* __restrict__ W2, const float* __restrict__ b2,
    const int* __restrict__ cnt, const int* __restrict__ tok_ids, const float* __restrict__ tok_w,
    float* __restrict__ out)
{
    int e = blockIdx.y;
    int n = cnt[e];
    int t0 = blockIdx.x * TM;
    if (t0 >= n) return;
    int tid = threadIdx.x;

    __shared__ int   s_tok[TM];
    __shared__ float s_w[TM];
    __shared__ float s_x[TM][KSTEP];
    __shared__ float s_w1[KSTEP][FFC];
    __shared__ float s_h[TM][FFC];

    if (tid < TM) {
        int idx = t0 + tid;
        s_tok[tid] = (idx < n) ? tok_ids[e * MAXTOK + idx] : -1;
        s_w[tid]   = (idx < n) ? tok_w[e * MAXTOK + idx] : 0.0f;
    }
    __syncthreads();

    float acc[TM][2];
    #pragma unroll
    for (int i = 0; i < TM; ++i) { acc[i][0] = 0.0f; acc[i][1] = 0.0f; }

    const float* W1e = W1 + (size_t)e * D_MODEL * D_FF;
    const float* W2e = W2 + (size_t)e * D_FF * D_MODEL;
    const float* b1e = b1 + (size_t)e * D_FF;

    int ffl = (tid & 63) * 2;
    int g   = tid >> 6;

    int fb0 = blockIdx.z * (D_FF / 2);
    for (int fb = fb0; fb < fb0 + D_FF / 2; fb += FFC) {
        float bv0 = b1e[fb + ffl], bv1 = b1e[fb + ffl + 1];
        float hacc[4][2];
        #pragma unroll
        for (int j = 0; j < 4; ++j) { hacc[j][0] = bv0; hacc[j][1] = bv1; }

        for (int kb = 0; kb < D_MODEL; kb += KSTEP) {
            #pragma unroll
            for (int r = 0; r < 4; ++r) {
                int i = tid + 512 * r;
                int row = i >> 6, col = i & 63;
                int tok = s_tok[row];
                s_x[row][col] = (tok >= 0) ? x[(size_t)tok * D_MODEL + kb + col] : 0.0f;
            }
            #pragma unroll
            for (int r = 0; r < 16; ++r) {
                int i = tid + 512 * r;
                int row = i >> 7, col = i & 127;
                s_w1[row][col] = W1e[(size_t)(kb + row) * D_FF + fb + col];
            }
            __syncthreads();
            #pragma unroll 8
            for (int kk = 0; kk < KSTEP; ++kk) {
                float2 wv = *reinterpret_cast<const float2*>(&s_w1[kk][ffl]);
                #pragma unroll
                for (int j = 0; j < 4; ++j) {
                    float xv = s_x[g * 4 + j][kk];
                    hacc[j][0] += xv * wv.x;
                    hacc[j][1] += xv * wv.y;
                }
            }
            __syncthreads();
        }
        #pragma unroll
        for (int j = 0; j < 4; ++j) {
            #pragma unroll
            for (int p = 0; p < 2; ++p) {
                float v = hacc[j][p];
                v = 0.5f * v * (1.0f + erff(v * 0.70710678118654752f));
                s_h[g * 4 + j][ffl + p] = v;
            }
        }
        __syncthreads();
        for (int ff = 0; ff < FFC; ++ff) {
            const float* w2row = W2e + (size_t)(fb + ff) * D_MODEL;
            float wc0 = w2row[tid], wc1 = w2row[tid + 512];
            #pragma unroll
            for (int tt = 0; tt < TM; ++tt) {
                float hv = s_h[tt][ff];
                acc[tt][0] += hv * wc0;
                acc[tt][1] += hv * wc1;
            }
        }
        __syncthreads();
    }

    float bc0 = b2[(size_t)e * D_MODEL + tid];
    float bc1 = b2[(size_t)e * D_MODEL + tid + 512];
    if (blockIdx.z != 0) { bc0 = 0.0f; bc1 = 0.0f; }
    #pragma unroll
    for (int tt = 0; tt < TM; ++tt) {
        int tok = s_tok[tt];
        if (tok >= 0) {
            float w = s_w[tt];
            atomicAdd(&out[(size_t)tok * D_MODEL + tid],       w * (acc[tt][0] + bc0));
            atomicAdd(&out[(size_t)tok * D_MODEL + tid + 512], w * (acc[tt][1] + bc1));
        }
    }
}

extern "C" void kernel_launch(void* const* d_in, const int* in_sizes, int n_in,
                              void* d_out, int out_size, void* d_ws, size_t ws_size,
                              hipStream_t stream) {
    const float* x  = (const float*)d_in[0];
    const float* Wg = (const float*)d_in[1];
    const float* bg = (const float*)d_in[2];
    const float* W1 = (const float*)d_in[3];
    const float* b1 = (const float*)d_in[4];
    const float* W2 = (const float*)d_in[5];
    const float* b2 = (const float*)d_in[6];
    float* out = (float*)d_out;

    char* ws = (char*)d_ws;
    int*    cnt     = (int*)(ws + WS_CNT);
    int*    offp    = (int*)(ws + WS_OFFA);
    int*    tok_ids = (int*)(ws + WS_TOKIDS);
    float*  tok_w   = (float*)(ws + WS_TOKW);
    int*    rowtok  = (int*)(ws + WS_ROWTOK);
    float*  roww    = (float*)(ws + WS_ROWW);
    int*    tokexp  = (int*)(ws + WS_TOKEXP);

    hipMemsetAsync(cnt, 0, NE * sizeof(int), stream);
    gating_kernel<<<NTOK / 256, 256, 0, stream>>>(x, Wg, bg, cnt, tok_ids, tok_w, tokexp);

    if (ws_size >= WS_NEED_A) {
        ushort* Hb  = (ushort*)(ws + WS_H);
        ushort* W1T = (ushort*)(ws + WS_W1T);
        ushort* Xg  = (ushort*)(ws + WS_XG);
        ushort* W2T = (ushort*)(ws + WS_W2T);
        float*  Y   = (float*)(ws + WS_W1T);   // aliases dead W1T+Xg after gemm1
        const int nks = 2;

        scan256_kernel<<<1, 64, 0, stream>>>(cnt, offp);
        wconv_all<<<dim3(1024, 16), 256, 0, stream>>>(W1, W2, W1T, W2T);
        gather_kernel<<<dim3(32, NE), 256, 0, stream>>>(x, cnt, offp, tok_ids, tok_w, Xg, rowtok, roww);
        gemm1_256<<<MAXMT * 16, 512, 0, stream>>>(Xg, W1T, b1, offp, Hb);
        gemm2_256<<<MAXMT * 8, 512, 0, stream>>>(Hb, W2T, b2, offp, Y);
        combine_kernel<<<NTOK, 256, 0, stream>>>(Y, offp, tokexp, tok_w, out, nks);
    } else {
        hipMemsetAsync(out, 0, (size_t)out_size * sizeof(float), stream);
        dim3 grid(MAXTOK / TM, NE, 2);
        ffn_kernel<<<grid, 512, 0, stream>>>(x, W1, b1, W2, b2, cnt, tok_ids, tok_w, out);
    }
}